// Round 6
// baseline (356.394 us; speedup 1.0000x reference)
//
#include <hip/hip_runtime.h>
#include <math.h>

#define CUTOFF    0.3927f
#define TWO_PI_F  6.283185307179586f
#define INV_2PI_F 0.15915494309189535f
#define INV_SQRT2 0.7071067811865476f
#define NB        4
#define NNODE     2048
#define HD        128
#define S_TAB     256
#define SG        8
#define BINS      512

__device__ __forceinline__ float sigmoidf_(float x){ return 1.0f/(1.0f+__expf(-x)); }
__device__ __forceinline__ float siluf_(float x){ return x*sigmoidf_(x); }
__device__ __forceinline__ float ssiluf_(float x){ return siluf_(x)*(1.0f/0.6f); }

// bitwise mirror of numpy: x - TWO_PI*np.round(x/TWO_PI), all float32, no fma
__device__ __forceinline__ float wrap_np(float x){
    float t = __fdiv_rn(x, TWO_PI_F);
    float k = rintf(t);
    return __fsub_rn(x, __fmul_rn(TWO_PI_F, k));
}

__device__ __forceinline__ void gadd(float* p, float v){
    __hip_atomic_fetch_add(p, v, __ATOMIC_RELAXED, __HIP_MEMORY_SCOPE_AGENT);
}

// ---------------- grid barrier (all nblk blocks co-resident) ----------------
__device__ __forceinline__ void gbar(int* ctr, int ph, int nblk){
    __syncthreads();
    if (threadIdx.x == 0){
        __builtin_amdgcn_fence(__ATOMIC_RELEASE, "agent");
        __hip_atomic_fetch_add(ctr + ph, 1, __ATOMIC_RELAXED, __HIP_MEMORY_SCOPE_AGENT);
        while (__hip_atomic_load(ctr + ph, __ATOMIC_RELAXED, __HIP_MEMORY_SCOPE_AGENT) < nblk)
            __builtin_amdgcn_s_sleep(2);
        __builtin_amdgcn_fence(__ATOMIC_ACQUIRE, "agent");
    }
    __syncthreads();
}

// ---------------- table build: one block = (l, b, 8 samples) ----------------
struct TabSmem { float X[SG][HD+4]; float g[16]; int probe; };

__device__ __forceinline__ float4 gemv4(const float (*X)[HD+4], int sl,
                                        const float* __restrict__ W, int j0){
    float a0=0.f, a1=0.f, a2=0.f, a3=0.f;
    #pragma unroll 8
    for (int k=0;k<HD;k++){
        float x = X[sl][k];
        float4 w = *(const float4*)(W + k*HD + j0);
        a0 += x*w.x; a1 += x*w.y; a2 += x*w.z; a3 += x*w.w;
    }
    return make_float4(a0,a1,a2,a3);
}

__device__ void table_block(int blk, int tid,
                            const int* __restrict__ src, const float* __restrict__ globs_e,
                            int ne,
                            const float* __restrict__ W_e0, const float* __restrict__ W_r1,
                            const float* __restrict__ W_r2, const float* __restrict__ W_g,
                            const float* __restrict__ W_v1, const float* __restrict__ W_v2,
                            const float* __restrict__ W_vo, float* __restrict__ table,
                            TabSmem& sm){
    int sl = tid >> 5, jq = tid & 31, j0 = jq*4;
    int sg = blk & 31, b = (blk>>5)&3, l = blk>>7;

    // probe an edge of batch b to recover globs[b]
    if (tid == 0) sm.probe = 0x7fffffff;
    __syncthreads();
    int stride = ne >> 8; if (stride < 1) stride = 1;
    int e = tid*stride; if (e >= ne) e = ne-1;
    if ((src[e] >> 11) == b) atomicMin(&sm.probe, e);
    __syncthreads();
    int pe = sm.probe; if (pe == 0x7fffffff) pe = 0;
    if (tid < 16) sm.g[tid] = globs_e[(size_t)pe*16 + tid];
    __syncthreads();

    const float step = CUTOFF / (S_TAB - 1);
    float rd = (sg*SG + sl)*step;

    const float* We0 = W_e0 + l*17*HD;
    const float* Wr1 = W_r1 + l*HD*HD;
    const float* Wr2 = W_r2 + l*HD*HD;
    const float* Wg  = W_g  + l*HD;
    const float* Wv1 = W_v1 + l*HD*HD;
    const float* Wv2 = W_v2 + l*HD*HD;
    const float* Wvo = W_vo + l*HD;

    float4 p = make_float4(0,0,0,0);
    #pragma unroll
    for (int k=0;k<16;k++){
        float g = sm.g[k];
        float4 w = *(const float4*)(We0 + k*HD + j0);
        p.x += g*w.x; p.y += g*w.y; p.z += g*w.z; p.w += g*w.w;
    }
    float4 w16 = *(const float4*)(We0 + 16*HD + j0);
    float4 h;
    h.x = siluf_(ssiluf_(p.x + rd*w16.x));
    h.y = siluf_(ssiluf_(p.y + rd*w16.y));
    h.z = siluf_(ssiluf_(p.z + rd*w16.z));
    h.w = siluf_(ssiluf_(p.w + rd*w16.w));

    #define STORE4(v) { sm.X[sl][j0]=(v).x; sm.X[sl][j0+1]=(v).y; sm.X[sl][j0+2]=(v).z; sm.X[sl][j0+3]=(v).w; }
    #define SSILU4(v) make_float4(ssiluf_((v).x), ssiluf_((v).y), ssiluf_((v).z), ssiluf_((v).w))

    STORE4(h); __syncthreads();
    float4 t = gemv4(sm.X, sl, Wr1, j0); __syncthreads();
    t = SSILU4(t);
    STORE4(t); __syncthreads();
    float4 u = gemv4(sm.X, sl, Wr2, j0); __syncthreads();
    h.x = (h.x + ssiluf_(u.x))*INV_SQRT2;
    h.y = (h.y + ssiluf_(u.y))*INV_SQRT2;
    h.z = (h.z + ssiluf_(u.z))*INV_SQRT2;
    h.w = (h.w + ssiluf_(u.w))*INV_SQRT2;

    float4 wg = *(const float4*)(Wg + j0);
    float pg = h.x*wg.x + h.y*wg.y + h.z*wg.z + h.w*wg.w;
    #pragma unroll
    for (int off=16; off>0; off>>=1) pg += __shfl_xor(pg, off);
    float gt = sigmoidf_(pg);
    h.x*=gt; h.y*=gt; h.z*=gt; h.w*=gt;

    STORE4(h); __syncthreads();
    t = gemv4(sm.X, sl, Wv1, j0); __syncthreads();
    t = SSILU4(t);
    STORE4(t); __syncthreads();
    u = gemv4(sm.X, sl, Wv2, j0);
    float4 v;
    v.x = siluf_((h.x + ssiluf_(u.x))*INV_SQRT2);
    v.y = siluf_((h.y + ssiluf_(u.y))*INV_SQRT2);
    v.z = siluf_((h.z + ssiluf_(u.z))*INV_SQRT2);
    v.w = siluf_((h.w + ssiluf_(u.w))*INV_SQRT2);
    float4 wvo = *(const float4*)(Wvo + j0);
    float pv = v.x*wvo.x + v.y*wvo.y + v.z*wvo.z + v.w*wvo.w;
    #pragma unroll
    for (int off=16; off>0; off>>=1) pv += __shfl_xor(pv, off);
    if (jq == 0) table[(l*NB+b)*S_TAB + sg*SG + sl] = pv;
    #undef STORE4
    #undef SSILU4
}

// ---------------- per-edge message ------------------------------------------
__device__ __forceinline__ bool edge_msg(const float* __restrict__ tab_b,
                                         float rx, float ry, float rd, float sc,
                                         float& mx, float& my){
    float d = rd * (1.0f/CUTOFF);
    if (d >= 1.0f) return false;
    float d2 = d*d;
    float d5 = d2*d2*d;
    float env = 1.0f + d5*(-21.0f + d*(35.0f + d*(-15.0f)));
    float u = rd * ((float)(S_TAB-1)/CUTOFF);
    int i1 = (int)u; if (i1 > S_TAB-1) i1 = S_TAB-1;
    float fr = u - (float)i1;
    int im = i1-1 < 0 ? 0 : i1-1;
    int i2 = i1+1 > S_TAB-1 ? S_TAB-1 : i1+1;
    int i3 = i1+2 > S_TAB-1 ? S_TAB-1 : i1+2;
    float p0=tab_b[im], p1=tab_b[i1], p2=tab_b[i2], p3=tab_b[i3];
    float mij = p1 + 0.5f*fr*((p2-p0) + fr*((2.f*p0-5.f*p1+4.f*p2-p3)
                               + fr*(3.f*(p1-p2)+p3-p0)));
    float nrm = sqrtf(rx*rx + ry*ry);
    float inv = 1.0f / fmaxf(nrm, 1e-8f);
    float wmul = mij * env * sc * inv;
    mx = wmul*rx; my = wmul*ry;
    return true;
}

// ------- edge phase: src-segmented sum in LDS, answer[t] = -sum_{src=t} -----
__device__ void edge_phase(int layer, int tid, int blk, int ne, int chunk,
                           const float* __restrict__ rel_coors,
                           const int* __restrict__ src, const int* __restrict__ tgt,
                           const float* __restrict__ coors_cur, float sc,
                           const float* __restrict__ table_g, float* tab,
                           float* bins, float* __restrict__ dest){
    for (int i=tid;i<NB*S_TAB;i+=256) tab[i] = table_g[layer*NB*S_TAB + i];
    for (int i=tid;i<BINS*2;i+=256) bins[i] = 0.f;
    int e0 = blk*chunk;
    int e1 = e0 + chunk; if (e1 > ne) e1 = ne;
    int s0 = (e0 < e1) ? src[e0] : 0;
    __syncthreads();

    for (int e=e0+tid; e<e1; e+=256){
        int s = src[e];
        int b = s >> 11;
        float rx, ry;
        if (layer == 0){
            float2 rc = ((const float2*)rel_coors)[e];
            rx = rc.x; ry = rc.y;
        } else {
            int t = tgt[e];
            float2 ct = ((const float2*)coors_cur)[t];
            float2 cs = ((const float2*)coors_cur)[s];
            rx = ct.x - cs.x; ry = ct.y - cs.y;
            rx -= TWO_PI_F*rintf(rx*INV_2PI_F);
            ry -= TWO_PI_F*rintf(ry*INV_2PI_F);
        }
        float rd = rx*rx + ry*ry;
        float mx, my;
        if (edge_msg(tab + b*S_TAB, rx, ry, rd, sc, mx, my)){
            if (mx != 0.f || my != 0.f){
                int local = s - s0;
                if ((unsigned)local < BINS){
                    atomicAdd(&bins[local*2],   mx);
                    atomicAdd(&bins[local*2+1], my);
                } else {                       // pad tail / pathological span
                    gadd(&dest[2*s],   -mx);
                    gadd(&dest[2*s+1], -my);
                }
            }
        }
    }
    __syncthreads();
    if (e0 < e1){
        for (int i=tid;i<BINS;i+=256){
            float x = bins[i*2], y = bins[i*2+1];
            int n = s0 + i;
            if ((x != 0.f || y != 0.f) && n < NB*NNODE){
                gadd(&dest[2*n],   -x);
                gadd(&dest[2*n+1], -y);
            }
        }
    }
}

// ------- truncation correction: for dropped reverse-edges D -----------------
// answer -= msg(e) at BOTH endpoints, for every e in D (row-major tail).
__device__ void d_fix(int layer, int tid, int blk, int nblk, int ne,
                      const int* __restrict__ src, const int* __restrict__ tgt,
                      const float* __restrict__ coors0,   // membership (original)
                      const float* __restrict__ ccur,     // layer coords for msg
                      const float* __restrict__ tab, float sc,
                      float* __restrict__ dest){
    int ic = src[ne-1];
    if (ic == 0) return;                    // padded (no truncation)
    int bc = ic >> 11;
    int r0 = ic - (bc << 11);
    int jc = tgt[ne-1] - (bc << 11);
    const float2* c0 = ((const float2*)coors0) + (bc << 11);
    const float2* cL = ((const float2*)ccur)  + (bc << 11);
    const float* tb = tab + bc*S_TAB;

    for (int r = r0 + blk; r < NNODE; r += nblk){
        float2 ci = c0[r];
        int jstart = (r == r0) ? jc + 1 : 0;
        for (int j = jstart + tid; j < NNODE; j += 256){
            float2 cj = c0[j];
            float wx = wrap_np(__fsub_rn(cj.x, ci.x));
            float wy = wrap_np(__fsub_rn(cj.y, ci.y));
            float d2 = __fadd_rn(__fmul_rn(wx,wx), __fmul_rn(wy,wy));
            if (!(d2 > 0.0f && d2 <= CUTOFF)) continue;   // setup-exact membership
            float rx, ry, rd;
            if (layer == 0){ rx = wx; ry = wy; rd = d2; }
            else {
                float2 ai = cL[r], aj = cL[j];
                rx = aj.x - ai.x; ry = aj.y - ai.y;
                rx -= TWO_PI_F*rintf(rx*INV_2PI_F);
                ry -= TWO_PI_F*rintf(ry*INV_2PI_F);
                rd = rx*rx + ry*ry;
            }
            float mx, my;
            if (edge_msg(tb, rx, ry, rd, sc, mx, my)){
                if (mx != 0.f || my != 0.f){
                    int gi = (bc << 11) + r, gj = (bc << 11) + j;
                    gadd(&dest[2*gi],   -mx); gadd(&dest[2*gi+1], -my);
                    gadd(&dest[2*gj],   -mx); gadd(&dest[2*gj+1], -my);
                }
            }
        }
    }
}

// ---------------- the persistent mega-kernel --------------------------------
__global__ __launch_bounds__(256, 4)
void k_mega(const float* __restrict__ coors, const float* __restrict__ globs_e,
            const float* __restrict__ rel_coors,
            const float* __restrict__ W_e0, const float* __restrict__ W_r1,
            const float* __restrict__ W_r2, const float* __restrict__ W_g,
            const float* __restrict__ W_v1, const float* __restrict__ W_v2,
            const float* __restrict__ W_vo, const float* __restrict__ scale,
            const int* __restrict__ src, const int* __restrict__ tgt,
            int ne, int nblk, int chunk,
            float* __restrict__ table, float* __restrict__ coors1,
            int* __restrict__ ctr, float* __restrict__ out){
    __shared__ TabSmem tsm;
    __shared__ float tab[NB*S_TAB];
    __shared__ float bins[BINS*2];
    int tid = threadIdx.x, blk = blockIdx.x;

    // P0: table build (first 256 blocks) + seed coors1 = coors
    if (blk < 256)
        table_block(blk, tid, src, globs_e, ne, W_e0, W_r1, W_r2, W_g, W_v1,
                    W_v2, W_vo, table, tsm);
    for (int i = blk*256+tid; i < NB*NNODE*2; i += nblk*256) coors1[i] = coors[i];
    float sc0 = scale[0], sc1 = scale[1];
    gbar(ctr, 0, nblk);

    // P1: layer-0 messages into coors1 (+ truncation fix)
    edge_phase(0, tid, blk, ne, chunk, rel_coors, src, tgt, nullptr, sc0,
               table, tab, bins, coors1);
    d_fix(0, tid, blk, nblk, ne, src, tgt, coors, coors, tab, sc0, coors1);
    gbar(ctr, 1, nblk);

    // P2: seed out = coors1 (final layer-0 coords)
    for (int i = blk*256+tid; i < NB*NNODE*2; i += nblk*256) out[i] = coors1[i];
    gbar(ctr, 2, nblk);

    // P3: layer-1 messages into out (+ truncation fix)
    edge_phase(1, tid, blk, ne, chunk, rel_coors, src, tgt, coors1, sc1,
               table, tab, bins, out);
    d_fix(1, tid, blk, nblk, ne, src, tgt, coors, coors1, tab, sc1, out);
}

extern "C" void kernel_launch(void* const* d_in, const int* in_sizes, int n_in,
                              void* d_out, int out_size, void* d_ws, size_t ws_size,
                              hipStream_t stream){
    const float* coors     = (const float*)d_in[0];
    const float* globs_e   = (const float*)d_in[1];
    const float* rel_coors = (const float*)d_in[2];
    const float* W_e0      = (const float*)d_in[4];
    const float* W_r1      = (const float*)d_in[5];
    const float* W_r2      = (const float*)d_in[6];
    const float* W_g       = (const float*)d_in[7];
    const float* W_v1      = (const float*)d_in[8];
    const float* W_v2      = (const float*)d_in[9];
    const float* W_vo      = (const float*)d_in[10];
    const float* scale     = (const float*)d_in[11];
    const int*   src       = (const int*)d_in[12];
    const int*   tgt       = (const int*)d_in[13];

    int ne = in_sizes[12];

    char* w = (char*)d_ws;
    int*   ctr    = (int*)w;                        // 64 B
    float* table  = (float*)(w + 64);               // 8 KB
    float* coors1 = (float*)(w + 64 + 8192);        // 64 KB

    // size the persistent grid so co-residency is guaranteed by construction
    int maxb = 0;
    if (hipOccupancyMaxActiveBlocksPerMultiprocessor(&maxb, k_mega, 256, 0)
            != hipSuccess || maxb < 1) maxb = 1;
    if (maxb > 4) maxb = 4;
    int nblk = 256*maxb;
    int chunk = (ne + nblk - 1)/nblk;

    hipMemsetAsync(ctr, 0, 64, stream);
    k_mega<<<nblk, 256, 0, stream>>>(coors, globs_e, rel_coors, W_e0, W_r1,
                                     W_r2, W_g, W_v1, W_v2, W_vo, scale,
                                     src, tgt, ne, nblk, chunk,
                                     table, coors1, ctr, (float*)d_out);
}

// Round 7
// 185.074 us; speedup vs baseline: 1.9257x; 1.9257x over previous
//
#include <hip/hip_runtime.h>
#include <math.h>

#define CUTOFF    0.3927f
#define TWO_PI_F  6.283185307179586f
#define INV_2PI_F 0.15915494309189535f
#define INV_SQRT2 0.7071067811865476f
#define NB        4
#define NNODE     2048
#define HD        128
#define S_TAB     256
#define SG        8
#define BINS      512
#define PHSTRIDE  288          // ints per barrier phase region (9 lines x 32)

__device__ __forceinline__ float sigmoidf_(float x){ return 1.0f/(1.0f+__expf(-x)); }
__device__ __forceinline__ float siluf_(float x){ return x*sigmoidf_(x); }
__device__ __forceinline__ float ssiluf_(float x){ return siluf_(x)*(1.0f/0.6f); }

// bitwise mirror of numpy: x - TWO_PI*np.round(x/TWO_PI), all float32, no fma
__device__ __forceinline__ float wrap_np(float x){
    float t = __fdiv_rn(x, TWO_PI_F);
    float k = rintf(t);
    return __fsub_rn(x, __fmul_rn(TWO_PI_F, k));
}

__device__ __forceinline__ void gadd(float* p, float v){
    __hip_atomic_fetch_add(p, v, __ATOMIC_RELAXED, __HIP_MEMORY_SCOPE_AGENT);
}

// ------- hierarchical grid barrier: 8 sub-counters -> 1 master --------------
// nblk must be a multiple of 8. Each sub-line is 128B apart (no false sharing).
__device__ __forceinline__ void gbar2(int* base, int nblk){
    __syncthreads();
    if (threadIdx.x == 0){
        __builtin_amdgcn_fence(__ATOMIC_RELEASE, "agent");
        int sub = blockIdx.x & 7;
        int quota = nblk >> 3;
        int* sc = base + sub*32;
        int* master = base + 8*32;
        int old = __hip_atomic_fetch_add(sc, 1, __ATOMIC_RELAXED, __HIP_MEMORY_SCOPE_AGENT);
        if (old + 1 == quota){
            __builtin_amdgcn_fence(__ATOMIC_ACQ_REL, "agent");
            __hip_atomic_fetch_add(master, 1, __ATOMIC_RELAXED, __HIP_MEMORY_SCOPE_AGENT);
        }
        while (__hip_atomic_load(master, __ATOMIC_RELAXED, __HIP_MEMORY_SCOPE_AGENT) < 8)
            __builtin_amdgcn_s_sleep(16);
        __builtin_amdgcn_fence(__ATOMIC_ACQUIRE, "agent");
    }
    __syncthreads();
}

// ---------------- table build: one block = (l, b, 8 samples) ----------------
struct TabSmem { float X[SG][HD+4]; float g[16]; int probe; };

__device__ __forceinline__ float4 gemv4(const float (*X)[HD+4], int sl,
                                        const float* __restrict__ W, int j0){
    float a0=0.f, a1=0.f, a2=0.f, a3=0.f;
    #pragma unroll 8
    for (int k=0;k<HD;k++){
        float x = X[sl][k];
        float4 w = *(const float4*)(W + k*HD + j0);
        a0 += x*w.x; a1 += x*w.y; a2 += x*w.z; a3 += x*w.w;
    }
    return make_float4(a0,a1,a2,a3);
}

__device__ void table_block(int blk, int tid,
                            const int* __restrict__ src, const float* __restrict__ globs_e,
                            int ne,
                            const float* __restrict__ W_e0, const float* __restrict__ W_r1,
                            const float* __restrict__ W_r2, const float* __restrict__ W_g,
                            const float* __restrict__ W_v1, const float* __restrict__ W_v2,
                            const float* __restrict__ W_vo, float* __restrict__ table,
                            TabSmem& sm){
    int sl = tid >> 5, jq = tid & 31, j0 = jq*4;
    int sg = blk & 31, b = (blk>>5)&3, l = blk>>7;

    // probe an edge of batch b to recover globs[b]
    if (tid == 0) sm.probe = 0x7fffffff;
    __syncthreads();
    int stride = ne >> 8; if (stride < 1) stride = 1;
    int e = tid*stride; if (e >= ne) e = ne-1;
    if ((src[e] >> 11) == b) atomicMin(&sm.probe, e);
    __syncthreads();
    int pe = sm.probe; if (pe == 0x7fffffff) pe = 0;
    if (tid < 16) sm.g[tid] = globs_e[(size_t)pe*16 + tid];
    __syncthreads();

    const float step = CUTOFF / (S_TAB - 1);
    float rd = (sg*SG + sl)*step;

    const float* We0 = W_e0 + l*17*HD;
    const float* Wr1 = W_r1 + l*HD*HD;
    const float* Wr2 = W_r2 + l*HD*HD;
    const float* Wg  = W_g  + l*HD;
    const float* Wv1 = W_v1 + l*HD*HD;
    const float* Wv2 = W_v2 + l*HD*HD;
    const float* Wvo = W_vo + l*HD;

    float4 p = make_float4(0,0,0,0);
    #pragma unroll
    for (int k=0;k<16;k++){
        float g = sm.g[k];
        float4 w = *(const float4*)(We0 + k*HD + j0);
        p.x += g*w.x; p.y += g*w.y; p.z += g*w.z; p.w += g*w.w;
    }
    float4 w16 = *(const float4*)(We0 + 16*HD + j0);
    float4 h;
    h.x = siluf_(ssiluf_(p.x + rd*w16.x));
    h.y = siluf_(ssiluf_(p.y + rd*w16.y));
    h.z = siluf_(ssiluf_(p.z + rd*w16.z));
    h.w = siluf_(ssiluf_(p.w + rd*w16.w));

    #define STORE4(v) { sm.X[sl][j0]=(v).x; sm.X[sl][j0+1]=(v).y; sm.X[sl][j0+2]=(v).z; sm.X[sl][j0+3]=(v).w; }
    #define SSILU4(v) make_float4(ssiluf_((v).x), ssiluf_((v).y), ssiluf_((v).z), ssiluf_((v).w))

    STORE4(h); __syncthreads();
    float4 t = gemv4(sm.X, sl, Wr1, j0); __syncthreads();
    t = SSILU4(t);
    STORE4(t); __syncthreads();
    float4 u = gemv4(sm.X, sl, Wr2, j0); __syncthreads();
    h.x = (h.x + ssiluf_(u.x))*INV_SQRT2;
    h.y = (h.y + ssiluf_(u.y))*INV_SQRT2;
    h.z = (h.z + ssiluf_(u.z))*INV_SQRT2;
    h.w = (h.w + ssiluf_(u.w))*INV_SQRT2;

    float4 wg = *(const float4*)(Wg + j0);
    float pg = h.x*wg.x + h.y*wg.y + h.z*wg.z + h.w*wg.w;
    #pragma unroll
    for (int off=16; off>0; off>>=1) pg += __shfl_xor(pg, off);
    float gt = sigmoidf_(pg);
    h.x*=gt; h.y*=gt; h.z*=gt; h.w*=gt;

    STORE4(h); __syncthreads();
    t = gemv4(sm.X, sl, Wv1, j0); __syncthreads();
    t = SSILU4(t);
    STORE4(t); __syncthreads();
    u = gemv4(sm.X, sl, Wv2, j0);
    float4 v;
    v.x = siluf_((h.x + ssiluf_(u.x))*INV_SQRT2);
    v.y = siluf_((h.y + ssiluf_(u.y))*INV_SQRT2);
    v.z = siluf_((h.z + ssiluf_(u.z))*INV_SQRT2);
    v.w = siluf_((h.w + ssiluf_(u.w))*INV_SQRT2);
    float4 wvo = *(const float4*)(Wvo + j0);
    float pv = v.x*wvo.x + v.y*wvo.y + v.z*wvo.z + v.w*wvo.w;
    #pragma unroll
    for (int off=16; off>0; off>>=1) pv += __shfl_xor(pv, off);
    if (jq == 0) table[(l*NB+b)*S_TAB + sg*SG + sl] = pv;
    #undef STORE4
    #undef SSILU4
}

// ---------------- per-edge message ------------------------------------------
__device__ __forceinline__ bool edge_msg(const float* __restrict__ tab_b,
                                         float rx, float ry, float rd, float sc,
                                         float& mx, float& my){
    float d = rd * (1.0f/CUTOFF);
    if (d >= 1.0f) return false;
    float d2 = d*d;
    float d5 = d2*d2*d;
    float env = 1.0f + d5*(-21.0f + d*(35.0f + d*(-15.0f)));
    float u = rd * ((float)(S_TAB-1)/CUTOFF);
    int i1 = (int)u; if (i1 > S_TAB-1) i1 = S_TAB-1;
    float fr = u - (float)i1;
    int im = i1-1 < 0 ? 0 : i1-1;
    int i2 = i1+1 > S_TAB-1 ? S_TAB-1 : i1+1;
    int i3 = i1+2 > S_TAB-1 ? S_TAB-1 : i1+2;
    float p0=tab_b[im], p1=tab_b[i1], p2=tab_b[i2], p3=tab_b[i3];
    float mij = p1 + 0.5f*fr*((p2-p0) + fr*((2.f*p0-5.f*p1+4.f*p2-p3)
                               + fr*(3.f*(p1-p2)+p3-p0)));
    float nrm = sqrtf(rx*rx + ry*ry);
    float inv = 1.0f / fmaxf(nrm, 1e-8f);
    float wmul = mij * env * sc * inv;
    mx = wmul*rx; my = wmul*ry;
    return true;
}

// ------- edge phase: src-segmented sum in LDS, answer[t] = -sum_{src=t} -----
// accumulates -msg into dest1 (and dest2 if non-null)
__device__ void edge_phase(int layer, int tid, int blk, int ne, int chunk,
                           const float* __restrict__ rel_coors,
                           const int* __restrict__ src, const int* __restrict__ tgt,
                           const float* __restrict__ coors_cur, float sc,
                           const float* __restrict__ table_g, float* tab,
                           float* bins, float* __restrict__ dest1,
                           float* __restrict__ dest2){
    for (int i=tid;i<NB*S_TAB;i+=256) tab[i] = table_g[layer*NB*S_TAB + i];
    for (int i=tid;i<BINS*2;i+=256) bins[i] = 0.f;
    int e0 = blk*chunk;
    int e1 = e0 + chunk; if (e1 > ne) e1 = ne;
    int s0 = (e0 < e1) ? src[e0] : 0;
    __syncthreads();

    for (int e=e0+tid; e<e1; e+=256){
        int s = src[e];
        int b = s >> 11;
        float rx, ry;
        if (layer == 0){
            float2 rc = ((const float2*)rel_coors)[e];
            rx = rc.x; ry = rc.y;
        } else {
            int t = tgt[e];
            float2 ct = ((const float2*)coors_cur)[t];
            float2 cs = ((const float2*)coors_cur)[s];
            rx = ct.x - cs.x; ry = ct.y - cs.y;
            rx -= TWO_PI_F*rintf(rx*INV_2PI_F);
            ry -= TWO_PI_F*rintf(ry*INV_2PI_F);
        }
        float rd = rx*rx + ry*ry;
        float mx, my;
        if (edge_msg(tab + b*S_TAB, rx, ry, rd, sc, mx, my)){
            if (mx != 0.f || my != 0.f){
                int local = s - s0;
                if ((unsigned)local < BINS){
                    atomicAdd(&bins[local*2],   mx);
                    atomicAdd(&bins[local*2+1], my);
                } else {                       // pathological span
                    gadd(&dest1[2*s],   -mx);
                    gadd(&dest1[2*s+1], -my);
                    if (dest2){ gadd(&dest2[2*s], -mx); gadd(&dest2[2*s+1], -my); }
                }
            }
        }
    }
    __syncthreads();
    if (e0 < e1){
        for (int i=tid;i<BINS;i+=256){
            float x = bins[i*2], y = bins[i*2+1];
            int n = s0 + i;
            if ((x != 0.f || y != 0.f) && n < NB*NNODE){
                gadd(&dest1[2*n],   -x);
                gadd(&dest1[2*n+1], -y);
                if (dest2){ gadd(&dest2[2*n], -x); gadd(&dest2[2*n+1], -y); }
            }
        }
    }
}

// ------- truncation correction: for dropped reverse-edges D -----------------
// answer -= msg(e) at BOTH endpoints, for every e in D (row-major tail).
__device__ void d_fix(int layer, int tid, int blk, int nblk, int ne,
                      const int* __restrict__ src, const int* __restrict__ tgt,
                      const float* __restrict__ coors0,   // membership (original)
                      const float* __restrict__ ccur,     // layer coords for msg
                      const float* __restrict__ tab, float sc,
                      float* __restrict__ dest1, float* __restrict__ dest2){
    int ic = src[ne-1];
    if (ic == 0) return;                    // padded (no truncation)
    int bc = ic >> 11;
    int r0 = ic - (bc << 11);
    int jc = tgt[ne-1] - (bc << 11);
    const float2* c0 = ((const float2*)coors0) + (bc << 11);
    const float2* cL = ((const float2*)ccur)  + (bc << 11);
    const float* tb = tab + bc*S_TAB;

    for (int r = r0 + blk; r < NNODE; r += nblk){
        float2 ci = c0[r];
        int jstart = (r == r0) ? jc + 1 : 0;
        for (int j = jstart + tid; j < NNODE; j += 256){
            float2 cj = c0[j];
            float wx = wrap_np(__fsub_rn(cj.x, ci.x));
            float wy = wrap_np(__fsub_rn(cj.y, ci.y));
            float d2 = __fadd_rn(__fmul_rn(wx,wx), __fmul_rn(wy,wy));
            if (!(d2 > 0.0f && d2 <= CUTOFF)) continue;   // setup-exact membership
            float rx, ry, rd;
            if (layer == 0){ rx = wx; ry = wy; rd = d2; }
            else {
                float2 ai = cL[r], aj = cL[j];
                rx = aj.x - ai.x; ry = aj.y - ai.y;
                rx -= TWO_PI_F*rintf(rx*INV_2PI_F);
                ry -= TWO_PI_F*rintf(ry*INV_2PI_F);
                rd = rx*rx + ry*ry;
            }
            float mx, my;
            if (edge_msg(tb, rx, ry, rd, sc, mx, my)){
                if (mx != 0.f || my != 0.f){
                    int gi = (bc << 11) + r, gj = (bc << 11) + j;
                    gadd(&dest1[2*gi],   -mx); gadd(&dest1[2*gi+1], -my);
                    gadd(&dest1[2*gj],   -mx); gadd(&dest1[2*gj+1], -my);
                    if (dest2){
                        gadd(&dest2[2*gi], -mx); gadd(&dest2[2*gi+1], -my);
                        gadd(&dest2[2*gj], -mx); gadd(&dest2[2*gj+1], -my);
                    }
                }
            }
        }
    }
}

// ---------------- the persistent mega-kernel (2 grid barriers) --------------
__global__ __launch_bounds__(256, 2)
void k_mega(const float* __restrict__ coors, const float* __restrict__ globs_e,
            const float* __restrict__ rel_coors,
            const float* __restrict__ W_e0, const float* __restrict__ W_r1,
            const float* __restrict__ W_r2, const float* __restrict__ W_g,
            const float* __restrict__ W_v1, const float* __restrict__ W_v2,
            const float* __restrict__ W_vo, const float* __restrict__ scale,
            const int* __restrict__ src, const int* __restrict__ tgt,
            int ne, int nblk, int chunk,
            float* __restrict__ table, float* __restrict__ coors1,
            int* __restrict__ ctr, float* __restrict__ out){
    __shared__ TabSmem tsm;
    __shared__ float tab[NB*S_TAB];
    __shared__ float bins[BINS*2];
    int tid = threadIdx.x, blk = blockIdx.x;

    // P0: table build (blocks 0..255); seed coors1 = out = coors (later blocks)
    if (blk < 256)
        table_block(blk, tid, src, globs_e, ne, W_e0, W_r1, W_r2, W_g, W_v1,
                    W_v2, W_vo, table, tsm);
    {
        int sblk = (nblk > 256) ? blk - 256 : blk;
        int stot = (nblk > 256) ? nblk - 256 : nblk;
        if (sblk >= 0)
            for (int i = sblk*256+tid; i < NB*NNODE*2; i += stot*256){
                float c = coors[i];
                coors1[i] = c; out[i] = c;
            }
    }
    float sc0 = scale[0], sc1 = scale[1];
    gbar2(ctr, nblk);

    // P1: layer-0 messages into BOTH coors1 and out (+ truncation fix)
    edge_phase(0, tid, blk, ne, chunk, rel_coors, src, tgt, nullptr, sc0,
               table, tab, bins, coors1, out);
    d_fix(0, tid, blk, nblk, ne, src, tgt, coors, coors, tab, sc0, coors1, out);
    gbar2(ctr + PHSTRIDE, nblk);

    // P2: layer-1 messages into out (+ truncation fix), reading coors1
    edge_phase(1, tid, blk, ne, chunk, rel_coors, src, tgt, coors1, sc1,
               table, tab, bins, out, nullptr);
    d_fix(1, tid, blk, nblk, ne, src, tgt, coors, coors1, tab, sc1, out, nullptr);
}

extern "C" void kernel_launch(void* const* d_in, const int* in_sizes, int n_in,
                              void* d_out, int out_size, void* d_ws, size_t ws_size,
                              hipStream_t stream){
    const float* coors     = (const float*)d_in[0];
    const float* globs_e   = (const float*)d_in[1];
    const float* rel_coors = (const float*)d_in[2];
    const float* W_e0      = (const float*)d_in[4];
    const float* W_r1      = (const float*)d_in[5];
    const float* W_r2      = (const float*)d_in[6];
    const float* W_g       = (const float*)d_in[7];
    const float* W_v1      = (const float*)d_in[8];
    const float* W_v2      = (const float*)d_in[9];
    const float* W_vo      = (const float*)d_in[10];
    const float* scale     = (const float*)d_in[11];
    const int*   src       = (const int*)d_in[12];
    const int*   tgt       = (const int*)d_in[13];

    int ne = in_sizes[12];

    char* w = (char*)d_ws;
    int*   ctr    = (int*)w;                        // 2 phases x 288 ints (<4KB)
    float* table  = (float*)(w + 4096);             // 8 KB
    float* coors1 = (float*)(w + 4096 + 8192);      // 64 KB

    // persistent grid: 2 blocks/CU if they fit, else 1 (must be mult of 8)
    int maxb = 0;
    if (hipOccupancyMaxActiveBlocksPerMultiprocessor(&maxb, k_mega, 256, 0)
            != hipSuccess || maxb < 1) maxb = 1;
    if (maxb > 2) maxb = 2;
    int nblk = 256*maxb;
    int chunk = (ne + nblk - 1)/nblk;

    hipMemsetAsync(ctr, 0, 4096, stream);
    k_mega<<<nblk, 256, 0, stream>>>(coors, globs_e, rel_coors, W_e0, W_r1,
                                     W_r2, W_g, W_v1, W_v2, W_vo, scale,
                                     src, tgt, ne, nblk, chunk,
                                     table, coors1, ctr, (float*)d_out);
}